// Round 14
// baseline (101.879 us; speedup 1.0000x reference)
//
#include <hip/hip_runtime.h>
#include <math.h>

#define HW 384
#define PLANE (HW*HW)   // 147456

// ---- workspace layout (float-index offsets) ----
// WT1R: 8 groups x 900  [gw][c*25+tap][4o]   (oc = gw*4 + o, gw = half*4+wu)
#define WT1_OFF   0                         // 7200
#define SC1_OFF   7296                      // 32
#define SH1_OFF   7328                      // 32
// WT2R: 8 groups x 800  [gw2][cc2][tap][8o] (gw2 = hf*4+wu, cab = hf*16+wu*4+cc2)
#define WT2_OFF   7360                      // 6400
#define SC2_OFF   13760                     // 8
#define SH2_OFF   13768                     // 8
#define W3_OFF    13776                     // 200
#define SC3_OFF   13976                     // 1
#define SH3_OFF   13977                     // 1
#define FWT_OFF   13984                     // 6860: [s][20] (k=o*4+c in 0..15, pad 16..19)
#define H1_OFF    32768                     // 32*PLANE
#define H2P_OFF   (32768 + 32*PLANE)        // 16*PLANE raw partials (2 halves x 8 outs)
#define H2S_OFF   (32768 + 48*PLANE)        // 8*PLANE combined BN'd h2

// ---------------- prep ----------------
__global__ void prep_kernel(
    const float* __restrict__ c1w, const float* __restrict__ c1b,
    const float* __restrict__ g1, const float* __restrict__ b1,
    const float* __restrict__ m1, const float* __restrict__ v1,
    const float* __restrict__ c2w, const float* __restrict__ c2b,
    const float* __restrict__ g2, const float* __restrict__ b2,
    const float* __restrict__ m2, const float* __restrict__ v2,
    const float* __restrict__ c3w, const float* __restrict__ c3b,
    const float* __restrict__ g3, const float* __restrict__ b3,
    const float* __restrict__ m3, const float* __restrict__ v3,
    const float* __restrict__ fw, float* __restrict__ W)
{
    int gid = blockIdx.x * 256 + threadIdx.x;
    int gstr = gridDim.x * 256;
    // conv1 weights: [gw*900 + (c*25+tap)*4 + o], oc = gw*4+o
    for (int i = gid; i < 7200; i += gstr) {
        int gw = i / 900, r = i % 900;
        int ct = r >> 2, o = r & 3;
        int oc = gw * 4 + o;
        W[WT1_OFF + i] = c1w[oc * 225 + ct];
    }
    // conv2 weights: [gw2*800 + cc2*200 + tap*8 + o], cab = (gw2>>2)*16 + (gw2&3)*4 + cc2
    for (int i = gid; i < 6400; i += gstr) {
        int gw2 = i / 800, r = i % 800;
        int cc2 = r / 200, r2 = r % 200, tap = r2 >> 3, o = r2 & 7;
        int cab = (gw2 >> 2) * 16 + (gw2 & 3) * 4 + cc2;
        W[WT2_OFF + i] = c2w[o * 800 + cab * 25 + tap];
    }
    // f_w: OIDHW (4,4,7,7,7) -> [s][20] padded rows (k = o*4+c)
    for (int i = gid; i < 6860; i += gstr) {
        int s = i / 20, k = i % 20;
        float v = 0.f;
        if (k < 16) { int o = k >> 2, c = k & 3; v = fw[o * 1372 + c * 343 + s]; }
        W[FWT_OFF + i] = v;
    }
    if (blockIdx.x == 0) {
        int tid = threadIdx.x;
        if (tid < 32) {
            float sc = g1[tid] / sqrtf(v1[tid] + 1e-5f);
            W[SC1_OFF + tid] = sc;
            W[SH1_OFF + tid] = (c1b[tid] - m1[tid]) * sc + b1[tid];
        }
        if (tid < 8) {
            float sc = g2[tid] / sqrtf(v2[tid] + 1e-5f);
            W[SC2_OFF + tid] = sc;
            W[SH2_OFF + tid] = (c2b[tid] - m2[tid]) * sc + b2[tid];
        }
        if (tid < 200) W[W3_OFF + tid] = c3w[tid];
        if (tid == 0) {
            float sc = g3[0] / sqrtf(v3[0] + 1e-5f);
            W[SC3_OFF] = sc;
            W[SH3_OFF] = (c3b[0] - m3[0]) * sc + b3[0];
        }
    }
}

// ---------------- conv1: 9 -> 32, 5x5, BN+ReLU (R12-proven form) ----------------
// grid 1152 = 576 spatial x 2 output-halves of 16. 4 waves x 4 outs, 4 px.
__global__ __launch_bounds__(256, 4) void conv1_kernel(
    const float* __restrict__ light, const float* __restrict__ albedo,
    const float* __restrict__ normals, const float* __restrict__ W,
    float* __restrict__ h1)
{
    __shared__ __align__(16) float tile[9 * 432];   // 15.6 KB
    int tid = threadIdx.x;
    int wu = __builtin_amdgcn_readfirstlane(tid >> 6);   // 0..3, uniform
    int slot = tid & 63;
    int qx = slot & 7, ty = slot >> 3;
    int bid = blockIdx.x;
    int half = bid & 1, sp = bid >> 1;
    int bx = sp % 12, by = sp / 12;
    int x0 = bx * 32, y0 = by * 8;

    for (int p = tid; p < 432; p += 256) {
        int py = p / 36, px = p % 36;
        int gy = y0 + py - 2, gx = x0 + px - 2;
        bool ok = ((unsigned)gy < (unsigned)HW) && ((unsigned)gx < (unsigned)HW);
        int gofs = ok ? (gy * HW + gx) : 0;
#pragma unroll
        for (int c = 0; c < 3; ++c) {
            float a = light[c * PLANE + gofs];
            float b = albedo[c * PLANE + gofs];
            float n = normals[c * PLANE + gofs];
            tile[(c    ) * 432 + p] = ok ? a : 0.f;
            tile[(c + 3) * 432 + p] = ok ? b : 0.f;
            tile[(c + 6) * 432 + p] = ok ? n : 0.f;
        }
    }
    __syncthreads();

    float acc[4][4];
#pragma unroll
    for (int o = 0; o < 4; ++o)
#pragma unroll
        for (int j = 0; j < 4; ++j) acc[o][j] = 0.f;

    int gw = half * 4 + wu;
    const float* wbase = W + WT1_OFF + gw * 900;   // contiguous per wave -> s_load
#pragma unroll 1
    for (int c = 0; c < 9; ++c) {
        const float* bc = tile + c * 432;
        const float* wc = wbase + c * 100;
#pragma unroll
        for (int ky = 0; ky < 5; ++ky) {
            const float* rp = bc + (ty + ky) * 36 + qx * 4;
            float4 ra = *(const float4*)rp;
            float4 rb = *(const float4*)(rp + 4);
            float row[8] = {ra.x, ra.y, ra.z, ra.w, rb.x, rb.y, rb.z, rb.w};
#pragma unroll
            for (int kx = 0; kx < 5; ++kx) {
                float4 wA = *(const float4*)(wc + (ky * 5 + kx) * 4);
#pragma unroll
                for (int j = 0; j < 4; ++j) {
                    float v = row[kx + j];
                    acc[0][j] = fmaf(v, wA.x, acc[0][j]);
                    acc[1][j] = fmaf(v, wA.y, acc[1][j]);
                    acc[2][j] = fmaf(v, wA.z, acc[2][j]);
                    acc[3][j] = fmaf(v, wA.w, acc[3][j]);
                }
            }
        }
    }

    int pix = (y0 + ty) * HW + x0 + qx * 4;
#pragma unroll
    for (int o = 0; o < 4; ++o) {
        int oc = gw * 4 + o;
        float sc = W[SC1_OFF + oc], sh = W[SH1_OFF + oc];
        float4 rv;
        rv.x = fmaxf(fmaf(acc[o][0], sc, sh), 0.f);
        rv.y = fmaxf(fmaf(acc[o][1], sc, sh), 0.f);
        rv.z = fmaxf(fmaf(acc[o][2], sc, sh), 0.f);
        rv.w = fmaxf(fmaf(acc[o][3], sc, sh), 0.f);
        *(float4*)&h1[oc * PLANE + pix] = rv;
    }
}

// ---------------- conv2: 32 -> 8, 5x5 -> raw half-partials ----------------
// grid 1152 = 576 spatial x 2 input-halves of 16 ch. Wave wu -> channels
// {4wu..4wu+3}, 8 outs, 4 px. Scalar weights; 2-round in-LDS fold.
__global__ __launch_bounds__(256, 4) void conv2_kernel(
    const float* __restrict__ h1, const float* __restrict__ W,
    float* __restrict__ h2p)
{
    __shared__ __align__(16) float lds[16 * 432];   // 27.6 KB; fold zones reuse
    int tid = threadIdx.x;
    int wu = __builtin_amdgcn_readfirstlane(tid >> 6);
    int slot = tid & 63;
    int qx = slot & 7, ty = slot >> 3;
    int bid = blockIdx.x;
    int hf = bid & 1, sp = bid >> 1;
    int bx = sp % 12, by = sp / 12;
    int x0 = bx * 32, y0 = by * 8;
    int cbase = hf * 16;

    for (int p = tid; p < 432; p += 256) {
        int py = p / 36, px = p % 36;
        int gy = y0 + py - 2, gx = x0 + px - 2;
        bool ok = ((unsigned)gy < (unsigned)HW) && ((unsigned)gx < (unsigned)HW);
        int gofs = ok ? (gy * HW + gx) : 0;
#pragma unroll 4
        for (int cc = 0; cc < 16; ++cc) {
            float v = h1[(cbase + cc) * PLANE + gofs];
            lds[cc * 432 + p] = ok ? v : 0.f;
        }
    }
    __syncthreads();

    float acc[8][4];
#pragma unroll
    for (int o = 0; o < 8; ++o)
#pragma unroll
        for (int j = 0; j < 4; ++j) acc[o][j] = 0.f;

    int gw2 = hf * 4 + wu;
#pragma unroll 1
    for (int cc2 = 0; cc2 < 4; ++cc2) {
        const float* bc = lds + (4 * wu + cc2) * 432;
        const float* wc = W + WT2_OFF + gw2 * 800 + cc2 * 200;   // contiguous per wave
#pragma unroll
        for (int ky = 0; ky < 5; ++ky) {
            const float* rp = bc + (ty + ky) * 36 + qx * 4;
            float4 ra = *(const float4*)rp;
            float4 rb = *(const float4*)(rp + 4);
            float row[8] = {ra.x, ra.y, ra.z, ra.w, rb.x, rb.y, rb.z, rb.w};
#pragma unroll
            for (int kx = 0; kx < 5; ++kx) {
                const float* wt = wc + (ky * 5 + kx) * 8;
                float4 wA = *(const float4*)wt;
                float4 wB = *(const float4*)(wt + 4);
#pragma unroll
                for (int j = 0; j < 4; ++j) {
                    float v = row[kx + j];
                    acc[0][j] = fmaf(v, wA.x, acc[0][j]);
                    acc[1][j] = fmaf(v, wA.y, acc[1][j]);
                    acc[2][j] = fmaf(v, wA.z, acc[2][j]);
                    acc[3][j] = fmaf(v, wA.w, acc[3][j]);
                    acc[4][j] = fmaf(v, wB.x, acc[4][j]);
                    acc[5][j] = fmaf(v, wB.y, acc[5][j]);
                    acc[6][j] = fmaf(v, wB.z, acc[6][j]);
                    acc[7][j] = fmaf(v, wB.w, acc[7][j]);
                }
            }
        }
    }
    __syncthreads();   // tile reads done; LDS reusable for fold zones

    if (wu >= 2) {
        float* pp = lds + (wu - 2) * 2304 + slot * 36;
#pragma unroll
        for (int o = 0; o < 8; ++o)
            *(float4*)(pp + o * 4) = make_float4(acc[o][0], acc[o][1], acc[o][2], acc[o][3]);
    }
    __syncthreads();
    if (wu < 2) {
        const float* pp = lds + wu * 2304 + slot * 36;
#pragma unroll
        for (int o = 0; o < 8; ++o) {
            float4 t = *(const float4*)(pp + o * 4);
            acc[o][0] += t.x; acc[o][1] += t.y; acc[o][2] += t.z; acc[o][3] += t.w;
        }
    }
    __syncthreads();
    if (wu == 1) {
        float* pp = lds + slot * 36;
#pragma unroll
        for (int o = 0; o < 8; ++o)
            *(float4*)(pp + o * 4) = make_float4(acc[o][0], acc[o][1], acc[o][2], acc[o][3]);
    }
    __syncthreads();
    if (wu == 0) {
        const float* pp = lds + slot * 36;
        int pix = (y0 + ty) * HW + x0 + qx * 4;
#pragma unroll
        for (int o = 0; o < 8; ++o) {
            float4 t = *(const float4*)(pp + o * 4);
            float4 rv;
            rv.x = acc[o][0] + t.x; rv.y = acc[o][1] + t.y;
            rv.z = acc[o][2] + t.z; rv.w = acc[o][3] + t.w;
            *(float4*)&h2p[(hf * 8 + o) * PLANE + pix] = rv;
        }
    }
}

// ---------------- combine: 16 partial planes -> 8 BN+ReLU planes ----------------
__global__ __launch_bounds__(256) void combine_kernel(
    const float* __restrict__ h2p, const float* __restrict__ W,
    float* __restrict__ h2)
{
    int i = blockIdx.x * 256 + threadIdx.x;      // 0 .. 294911
    int o = i / (PLANE / 4);                     // 0..7
    int p4 = i - o * (PLANE / 4);
    int idx = o * PLANE + p4 * 4;
    float4 t0 = *(const float4*)&h2p[idx];
    float4 t1 = *(const float4*)&h2p[idx + 8 * PLANE];
    float s0 = t0.x + t1.x;
    float s1 = t0.y + t1.y;
    float s2 = t0.z + t1.z;
    float s3 = t0.w + t1.w;
    float sc = W[SC2_OFF + o], sh = W[SH2_OFF + o];
    float4 rv;
    rv.x = fmaxf(fmaf(s0, sc, sh), 0.f);
    rv.y = fmaxf(fmaf(s1, sc, sh), 0.f);
    rv.z = fmaxf(fmaf(s2, sc, sh), 0.f);
    rv.w = fmaxf(fmaf(s3, sc, sh), 0.f);
    *(float4*)&h2[idx] = rv;
}

// ---------------- final (fused conv3): stage h2 8-plane halo, conv3+sigmoid
// +floor -> depth tile, then sparse 3d gather. (R12-proven) ----------------
__global__ __launch_bounds__(256, 4) void final_kernel(
    const float* __restrict__ light, const float* __restrict__ albedo,
    const float* __restrict__ h2, const float* __restrict__ W,
    const float* __restrict__ fb, float* __restrict__ out)
{
    __shared__ __align__(16) float u[6860];     // phase1: h2t [8][18][42]=6048; phase3: fwl [343][20]
    __shared__ float ltile[3][14][38];
    __shared__ int   dtile[14][38];

    int tid = threadIdx.x;
    int tx = tid & 31, ty = tid >> 5;
    int bx = blockIdx.x % 12, by = blockIdx.x / 12;
    int x0 = bx * 32 - 3, y0 = by * 8 - 3;     // dtile/ltile origin
    int x2 = x0 - 2, y2 = y0 - 2;              // h2t origin (conv3 halo)

    // phase 1a: stage h2 over 18x42
    for (int p = tid; p < 756; p += 256) {
        int r = p / 42, cpx = p % 42;
        int gy = y2 + r, gx = x2 + cpx;
        bool ok = ((unsigned)gy < (unsigned)HW) && ((unsigned)gx < (unsigned)HW);
        int gofs = ok ? (gy * HW + gx) : 0;
#pragma unroll
        for (int c = 0; c < 8; ++c) {
            float v = h2[c * PLANE + gofs];
            u[c * 756 + p] = ok ? v : 0.f;
        }
    }
    // phase 1b: stage light tile
    for (int p = tid; p < 532; p += 256) {
        int py = p / 38, px = p % 38;
        int gy = y0 + py, gx = x0 + px;
        bool ok = ((unsigned)gy < (unsigned)HW) && ((unsigned)gx < (unsigned)HW);
        int gofs = ok ? (gy * HW + gx) : 0;
#pragma unroll
        for (int c = 0; c < 3; ++c) {
            float lv = light[c * PLANE + gofs];
            ltile[c][py][px] = ok ? lv : 0.f;
        }
    }
    __syncthreads();

    // phase 2: conv3 -> depth over 14x38
    for (int p = tid; p < 532; p += 256) {
        int py = p / 38, px = p % 38;
        int gy = y0 + py, gx = x0 + px;
        bool ok = ((unsigned)gy < (unsigned)HW) && ((unsigned)gx < (unsigned)HW);
        int d = -1000;
        if (ok) {
            float a = 0.f;
#pragma unroll 1
            for (int c = 0; c < 8; ++c) {
#pragma unroll
                for (int ky = 0; ky < 5; ++ky) {
#pragma unroll
                    for (int kx = 0; kx < 5; ++kx) {
                        a = fmaf(u[c * 756 + (py + ky) * 42 + (px + kx)],
                                 W[W3_OFF + (c * 5 + ky) * 5 + kx], a);
                    }
                }
            }
            float y = fmaf(a, W[SC3_OFF], W[SH3_OFF]);
            float s = 1.f / (1.f + expf(-y));
            d = (int)floorf(s * (16.f - 1e-5f));
        }
        dtile[py][px] = d;
    }
    __syncthreads();

    // phase 3: overwrite u with fwl [s][20] (stride-20 -> conflict-free b128)
    for (int i = tid; i < 6860; i += 256) u[i] = W[FWT_OFF + i];
    __syncthreads();

    // phase 4: sparse 3d gather
    int d0 = dtile[ty + 3][tx + 3];
    float a0 = fb[0], a1 = fb[1], a2 = fb[2], a3 = fb[3];

#pragma unroll 1
    for (int dy = 0; dy < 7; ++dy) {
#pragma unroll
        for (int dx = 0; dx < 7; ++dx) {
            int dd = dtile[ty + dy][tx + dx];
            int dz = dd - d0 + 3;
            if ((unsigned)dz < 7u) {
                int s = (dz * 7 + dy) * 7 + dx;
                const float* fs = u + s * 20;   // k = o*4 + c
                float4 w0 = *(const float4*)(fs);
                float4 w1 = *(const float4*)(fs + 4);
                float4 w2 = *(const float4*)(fs + 8);
                float4 w3 = *(const float4*)(fs + 12);
                float l0 = ltile[0][ty + dy][tx + dx];
                float l1 = ltile[1][ty + dy][tx + dx];
                float l2 = ltile[2][ty + dy][tx + dx];
                a0 += l0 * w0.x + l1 * w0.y + l2 * w0.z + w0.w;
                a1 += l0 * w1.x + l1 * w1.y + l2 * w1.z + w1.w;
                a2 += l0 * w2.x + l1 * w2.y + l2 * w2.z + w2.w;
                a3 += l0 * w3.x + l1 * w3.y + l2 * w3.z + w3.w;
            }
        }
    }

    int gy = by * 8 + ty, gx = bx * 32 + tx;
    int pix = gy * HW + gx;
    out[0 * PLANE + pix] = a0 / a3 * albedo[0 * PLANE + pix];
    out[1 * PLANE + pix] = a1 / a3 * albedo[1 * PLANE + pix];
    out[2 * PLANE + pix] = a2 / a3 * albedo[2 * PLANE + pix];
}

extern "C" void kernel_launch(void* const* d_in, const int* in_sizes, int n_in,
                              void* d_out, int out_size, void* d_ws, size_t ws_size,
                              hipStream_t stream) {
    const float* light     = (const float*)d_in[0];
    const float* albedo    = (const float*)d_in[1];
    const float* normals   = (const float*)d_in[2];
    const float* c1_w = (const float*)d_in[4];
    const float* c1_b = (const float*)d_in[5];
    const float* bn1_g = (const float*)d_in[6];
    const float* bn1_b = (const float*)d_in[7];
    const float* bn1_m = (const float*)d_in[8];
    const float* bn1_v = (const float*)d_in[9];
    const float* c2_w = (const float*)d_in[10];
    const float* c2_b = (const float*)d_in[11];
    const float* bn2_g = (const float*)d_in[12];
    const float* bn2_b = (const float*)d_in[13];
    const float* bn2_m = (const float*)d_in[14];
    const float* bn2_v = (const float*)d_in[15];
    const float* c3_w = (const float*)d_in[16];
    const float* c3_b = (const float*)d_in[17];
    const float* bn3_g = (const float*)d_in[18];
    const float* bn3_b = (const float*)d_in[19];
    const float* bn3_m = (const float*)d_in[20];
    const float* bn3_v = (const float*)d_in[21];
    const float* f_w = (const float*)d_in[22];
    const float* f_b = (const float*)d_in[23];

    float* W = (float*)d_ws;
    float* h1 = W + H1_OFF;
    float* h2p = W + H2P_OFF;
    float* h2 = W + H2S_OFF;
    float* out = (float*)d_out;

    hipLaunchKernelGGL(prep_kernel, dim3(16), dim3(256), 0, stream,
                       c1_w, c1_b, bn1_g, bn1_b, bn1_m, bn1_v,
                       c2_w, c2_b, bn2_g, bn2_b, bn2_m, bn2_v,
                       c3_w, c3_b, bn3_g, bn3_b, bn3_m, bn3_v,
                       f_w, W);
    hipLaunchKernelGGL(conv1_kernel, dim3(1152), dim3(256), 0, stream,
                       light, albedo, normals, W, h1);
    hipLaunchKernelGGL(conv2_kernel, dim3(1152), dim3(256), 0, stream,
                       h1, W, h2p);
    hipLaunchKernelGGL(combine_kernel, dim3(1152), dim3(256), 0, stream,
                       h2p, W, h2);
    hipLaunchKernelGGL(final_kernel, dim3(576), dim3(256), 0, stream,
                       light, albedo, h2, W, f_b, out);
}

// Round 15
// 93.080 us; speedup vs baseline: 1.0945x; 1.0945x over previous
//
#include <hip/hip_runtime.h>
#include <math.h>

#define HW 384
#define PLANE (HW*HW)   // 147456

// ---- workspace layout (float-index offsets) ----
// WT1R: 8 groups x 900  [gw][c*25+tap][4o]   (oc = gw*4 + o, gw = half*4+wu)
#define WT1_OFF   0                         // 7200
#define SC1_OFF   7296                      // 32
#define SH1_OFF   7328                      // 32
// WT2R: 16 wave-groups x 400  [gw][cc2][tap][8o] (gw = q*4+wu, cab = q*8+2wu+cc2)
#define WT2_OFF   7360                      // 6400
#define SC2_OFF   13760                     // 8
#define SH2_OFF   13768                     // 8
#define W3_OFF    13776                     // 200
#define SC3_OFF   13976                     // 1
#define SH3_OFF   13977                     // 1
#define FWT_OFF   13984                     // 6860: [s][20] (k=o*4+c in 0..15, pad 16..19)
#define H1_OFF    32768                     // 32*PLANE
#define H2P_OFF   (32768 + 32*PLANE)        // 32*PLANE raw partials (4 quarters x 8 outs)
#define H2S_OFF   (32768 + 64*PLANE)        // 8*PLANE combined BN'd h2

// ---------------- prep (R12 verbatim) ----------------
__global__ void prep_kernel(
    const float* __restrict__ c1w, const float* __restrict__ c1b,
    const float* __restrict__ g1, const float* __restrict__ b1,
    const float* __restrict__ m1, const float* __restrict__ v1,
    const float* __restrict__ c2w, const float* __restrict__ c2b,
    const float* __restrict__ g2, const float* __restrict__ b2,
    const float* __restrict__ m2, const float* __restrict__ v2,
    const float* __restrict__ c3w, const float* __restrict__ c3b,
    const float* __restrict__ g3, const float* __restrict__ b3,
    const float* __restrict__ m3, const float* __restrict__ v3,
    const float* __restrict__ fw, float* __restrict__ W)
{
    int gid = blockIdx.x * 256 + threadIdx.x;
    int gstr = gridDim.x * 256;
    for (int i = gid; i < 7200; i += gstr) {
        int gw = i / 900, r = i % 900;
        int ct = r >> 2, o = r & 3;
        int oc = gw * 4 + o;
        W[WT1_OFF + i] = c1w[oc * 225 + ct];
    }
    for (int i = gid; i < 6400; i += gstr) {
        int gw = i / 400, r = i % 400;
        int cc2 = r / 200, r2 = r % 200, tap = r2 >> 3, o = r2 & 7;
        int cab = (gw >> 2) * 8 + (gw & 3) * 2 + cc2;
        W[WT2_OFF + i] = c2w[o * 800 + cab * 25 + tap];
    }
    for (int i = gid; i < 6860; i += gstr) {
        int s = i / 20, k = i % 20;
        float v = 0.f;
        if (k < 16) { int o = k >> 2, c = k & 3; v = fw[o * 1372 + c * 343 + s]; }
        W[FWT_OFF + i] = v;
    }
    if (blockIdx.x == 0) {
        int tid = threadIdx.x;
        if (tid < 32) {
            float sc = g1[tid] / sqrtf(v1[tid] + 1e-5f);
            W[SC1_OFF + tid] = sc;
            W[SH1_OFF + tid] = (c1b[tid] - m1[tid]) * sc + b1[tid];
        }
        if (tid < 8) {
            float sc = g2[tid] / sqrtf(v2[tid] + 1e-5f);
            W[SC2_OFF + tid] = sc;
            W[SH2_OFF + tid] = (c2b[tid] - m2[tid]) * sc + b2[tid];
        }
        if (tid < 200) W[W3_OFF + tid] = c3w[tid];
        if (tid == 0) {
            float sc = g3[0] / sqrtf(v3[0] + 1e-5f);
            W[SC3_OFF] = sc;
            W[SH3_OFF] = (c3b[0] - m3[0]) * sc + b3[0];
        }
    }
}

// ---------------- conv1 (R12 verbatim): 9 -> 32, 5x5, BN+ReLU ----------------
__global__ __launch_bounds__(256, 4) void conv1_kernel(
    const float* __restrict__ light, const float* __restrict__ albedo,
    const float* __restrict__ normals, const float* __restrict__ W,
    float* __restrict__ h1)
{
    __shared__ __align__(16) float tile[9 * 432];   // 15.6 KB
    int tid = threadIdx.x;
    int wu = __builtin_amdgcn_readfirstlane(tid >> 6);   // 0..3, uniform
    int slot = tid & 63;
    int qx = slot & 7, ty = slot >> 3;
    int bid = blockIdx.x;
    int half = bid & 1, sp = bid >> 1;
    int bx = sp % 12, by = sp / 12;
    int x0 = bx * 32, y0 = by * 8;

    for (int p = tid; p < 432; p += 256) {
        int py = p / 36, px = p % 36;
        int gy = y0 + py - 2, gx = x0 + px - 2;
        bool ok = ((unsigned)gy < (unsigned)HW) && ((unsigned)gx < (unsigned)HW);
        int gofs = ok ? (gy * HW + gx) : 0;
#pragma unroll
        for (int c = 0; c < 3; ++c) {
            float a = light[c * PLANE + gofs];
            float b = albedo[c * PLANE + gofs];
            float n = normals[c * PLANE + gofs];
            tile[(c    ) * 432 + p] = ok ? a : 0.f;
            tile[(c + 3) * 432 + p] = ok ? b : 0.f;
            tile[(c + 6) * 432 + p] = ok ? n : 0.f;
        }
    }
    __syncthreads();

    float acc[4][4];
#pragma unroll
    for (int o = 0; o < 4; ++o)
#pragma unroll
        for (int j = 0; j < 4; ++j) acc[o][j] = 0.f;

    int gw = half * 4 + wu;
    const float* wbase = W + WT1_OFF + gw * 900;
#pragma unroll 1
    for (int c = 0; c < 9; ++c) {
        const float* bc = tile + c * 432;
        const float* wc = wbase + c * 100;
#pragma unroll
        for (int ky = 0; ky < 5; ++ky) {
            const float* rp = bc + (ty + ky) * 36 + qx * 4;
            float4 ra = *(const float4*)rp;
            float4 rb = *(const float4*)(rp + 4);
            float row[8] = {ra.x, ra.y, ra.z, ra.w, rb.x, rb.y, rb.z, rb.w};
#pragma unroll
            for (int kx = 0; kx < 5; ++kx) {
                float4 wA = *(const float4*)(wc + (ky * 5 + kx) * 4);
#pragma unroll
                for (int j = 0; j < 4; ++j) {
                    float v = row[kx + j];
                    acc[0][j] = fmaf(v, wA.x, acc[0][j]);
                    acc[1][j] = fmaf(v, wA.y, acc[1][j]);
                    acc[2][j] = fmaf(v, wA.z, acc[2][j]);
                    acc[3][j] = fmaf(v, wA.w, acc[3][j]);
                }
            }
        }
    }

    int pix = (y0 + ty) * HW + x0 + qx * 4;
#pragma unroll
    for (int o = 0; o < 4; ++o) {
        int oc = gw * 4 + o;
        float sc = W[SC1_OFF + oc], sh = W[SH1_OFF + oc];
        float4 rv;
        rv.x = fmaxf(fmaf(acc[o][0], sc, sh), 0.f);
        rv.y = fmaxf(fmaf(acc[o][1], sc, sh), 0.f);
        rv.z = fmaxf(fmaf(acc[o][2], sc, sh), 0.f);
        rv.w = fmaxf(fmaf(acc[o][3], sc, sh), 0.f);
        *(float4*)&h1[oc * PLANE + pix] = rv;
    }
}

// ---------------- conv2 (R12 verbatim): 32 -> 8, 5x5 -> raw quarter-partials ----------------
__global__ __launch_bounds__(256, 4) void conv2_kernel(
    const float* __restrict__ h1, const float* __restrict__ W,
    float* __restrict__ h2p)
{
    __shared__ __align__(16) float lds[4608];
    int tid = threadIdx.x;
    int wu = __builtin_amdgcn_readfirstlane(tid >> 6);
    int slot = tid & 63;
    int qx = slot & 7, ty = slot >> 3;
    int bid = blockIdx.x;
    int q = bid & 3, sp = bid >> 2;
    int bx = sp % 12, by = sp / 12;
    int x0 = bx * 32, y0 = by * 8;
    int cbase = q * 8;

    for (int p = tid; p < 432; p += 256) {
        int py = p / 36, px = p % 36;
        int gy = y0 + py - 2, gx = x0 + px - 2;
        bool ok = ((unsigned)gy < (unsigned)HW) && ((unsigned)gx < (unsigned)HW);
        int gofs = ok ? (gy * HW + gx) : 0;
#pragma unroll
        for (int cc = 0; cc < 8; ++cc) {
            float v = h1[(cbase + cc) * PLANE + gofs];
            lds[cc * 432 + p] = ok ? v : 0.f;
        }
    }
    __syncthreads();

    float acc[8][4];
#pragma unroll
    for (int o = 0; o < 8; ++o)
#pragma unroll
        for (int j = 0; j < 4; ++j) acc[o][j] = 0.f;

    int gw = q * 4 + wu;
#pragma unroll 1
    for (int cc2 = 0; cc2 < 2; ++cc2) {
        const float* bc = lds + (2 * wu + cc2) * 432;
        const float* wc = W + WT2_OFF + gw * 400 + cc2 * 200;
#pragma unroll
        for (int ky = 0; ky < 5; ++ky) {
            const float* rp = bc + (ty + ky) * 36 + qx * 4;
            float4 ra = *(const float4*)rp;
            float4 rb = *(const float4*)(rp + 4);
            float row[8] = {ra.x, ra.y, ra.z, ra.w, rb.x, rb.y, rb.z, rb.w};
#pragma unroll
            for (int kx = 0; kx < 5; ++kx) {
                const float* wt = wc + (ky * 5 + kx) * 8;
                float4 wA = *(const float4*)wt;
                float4 wB = *(const float4*)(wt + 4);
#pragma unroll
                for (int j = 0; j < 4; ++j) {
                    float v = row[kx + j];
                    acc[0][j] = fmaf(v, wA.x, acc[0][j]);
                    acc[1][j] = fmaf(v, wA.y, acc[1][j]);
                    acc[2][j] = fmaf(v, wA.z, acc[2][j]);
                    acc[3][j] = fmaf(v, wA.w, acc[3][j]);
                    acc[4][j] = fmaf(v, wB.x, acc[4][j]);
                    acc[5][j] = fmaf(v, wB.y, acc[5][j]);
                    acc[6][j] = fmaf(v, wB.z, acc[6][j]);
                    acc[7][j] = fmaf(v, wB.w, acc[7][j]);
                }
            }
        }
    }
    __syncthreads();

    if (wu >= 2) {
        float* pp = lds + (wu - 2) * 2304 + slot * 36;
#pragma unroll
        for (int o = 0; o < 8; ++o)
            *(float4*)(pp + o * 4) = make_float4(acc[o][0], acc[o][1], acc[o][2], acc[o][3]);
    }
    __syncthreads();
    if (wu < 2) {
        const float* pp = lds + wu * 2304 + slot * 36;
#pragma unroll
        for (int o = 0; o < 8; ++o) {
            float4 t = *(const float4*)(pp + o * 4);
            acc[o][0] += t.x; acc[o][1] += t.y; acc[o][2] += t.z; acc[o][3] += t.w;
        }
    }
    __syncthreads();
    if (wu == 1) {
        float* pp = lds + slot * 36;
#pragma unroll
        for (int o = 0; o < 8; ++o)
            *(float4*)(pp + o * 4) = make_float4(acc[o][0], acc[o][1], acc[o][2], acc[o][3]);
    }
    __syncthreads();
    if (wu == 0) {
        const float* pp = lds + slot * 36;
        int pix = (y0 + ty) * HW + x0 + qx * 4;
#pragma unroll
        for (int o = 0; o < 8; ++o) {
            float4 t = *(const float4*)(pp + o * 4);
            float4 rv;
            rv.x = acc[o][0] + t.x; rv.y = acc[o][1] + t.y;
            rv.z = acc[o][2] + t.z; rv.w = acc[o][3] + t.w;
            *(float4*)&h2p[(q * 8 + o) * PLANE + pix] = rv;
        }
    }
}

// ---------------- combine (R12 verbatim): 32 partial planes -> 8 BN+ReLU planes ----------------
__global__ __launch_bounds__(256) void combine_kernel(
    const float* __restrict__ h2p, const float* __restrict__ W,
    float* __restrict__ h2)
{
    int i = blockIdx.x * 256 + threadIdx.x;      // 0 .. 294911
    int o = i / (PLANE / 4);                     // 0..7
    int p4 = i - o * (PLANE / 4);
    int idx = o * PLANE + p4 * 4;
    float4 t0 = *(const float4*)&h2p[idx];
    float4 t1 = *(const float4*)&h2p[idx + 8 * PLANE];
    float4 t2 = *(const float4*)&h2p[idx + 16 * PLANE];
    float4 t3 = *(const float4*)&h2p[idx + 24 * PLANE];
    float s0 = ((t0.x + t1.x) + t2.x) + t3.x;
    float s1 = ((t0.y + t1.y) + t2.y) + t3.y;
    float s2 = ((t0.z + t1.z) + t2.z) + t3.z;
    float s3 = ((t0.w + t1.w) + t2.w) + t3.w;
    float sc = W[SC2_OFF + o], sh = W[SH2_OFF + o];
    float4 rv;
    rv.x = fmaxf(fmaf(s0, sc, sh), 0.f);
    rv.y = fmaxf(fmaf(s1, sc, sh), 0.f);
    rv.z = fmaxf(fmaf(s2, sc, sh), 0.f);
    rv.w = fmaxf(fmaf(s3, sc, sh), 0.f);
    *(float4*)&h2[idx] = rv;
}

// ---------------- final (fused conv3), 512 threads: gather split across
// wave-pairs (lower: dy0-3 + f_b, upper: dy4-6), LDS float4 reduce. ----------------
__global__ __launch_bounds__(512, 2) void final_kernel(
    const float* __restrict__ light, const float* __restrict__ albedo,
    const float* __restrict__ h2, const float* __restrict__ W,
    const float* __restrict__ fb, float* __restrict__ out)
{
    __shared__ __align__(16) float u[6860];     // phase1: h2t [8][18][42]=6048; phase3: fwl [343][20]
    __shared__ float ltile[3][14][38];
    __shared__ int   dtile[14][38];
    __shared__ __align__(16) float red[256 * 4];

    int tid = threadIdx.x;
    int hi = tid >> 8;                  // 0 = lower half, 1 = upper half
    int pslot = tid & 255;
    int tx = pslot & 31, ty = pslot >> 5;
    int bx = blockIdx.x % 12, by = blockIdx.x / 12;
    int x0 = bx * 32 - 3, y0 = by * 8 - 3;     // dtile/ltile origin
    int x2 = x0 - 2, y2 = y0 - 2;              // h2t origin (conv3 halo)

    // phase 1a: stage h2 over 18x42 (512-thread stride)
    for (int p = tid; p < 756; p += 512) {
        int r = p / 42, cpx = p % 42;
        int gy = y2 + r, gx = x2 + cpx;
        bool ok = ((unsigned)gy < (unsigned)HW) && ((unsigned)gx < (unsigned)HW);
        int gofs = ok ? (gy * HW + gx) : 0;
#pragma unroll
        for (int c = 0; c < 8; ++c) {
            float v = h2[c * PLANE + gofs];
            u[c * 756 + p] = ok ? v : 0.f;
        }
    }
    // phase 1b: stage light tile
    for (int p = tid; p < 532; p += 512) {
        int py = p / 38, px = p % 38;
        int gy = y0 + py, gx = x0 + px;
        bool ok = ((unsigned)gy < (unsigned)HW) && ((unsigned)gx < (unsigned)HW);
        int gofs = ok ? (gy * HW + gx) : 0;
#pragma unroll
        for (int c = 0; c < 3; ++c) {
            float lv = light[c * PLANE + gofs];
            ltile[c][py][px] = ok ? lv : 0.f;
        }
    }
    __syncthreads();

    // phase 2: conv3 -> depth over 14x38 (512-thread stride)
    for (int p = tid; p < 532; p += 512) {
        int py = p / 38, px = p % 38;
        int gy = y0 + py, gx = x0 + px;
        bool ok = ((unsigned)gy < (unsigned)HW) && ((unsigned)gx < (unsigned)HW);
        int d = -1000;
        if (ok) {
            float a = 0.f;
#pragma unroll 1
            for (int c = 0; c < 8; ++c) {
#pragma unroll
                for (int ky = 0; ky < 5; ++ky) {
#pragma unroll
                    for (int kx = 0; kx < 5; ++kx) {
                        a = fmaf(u[c * 756 + (py + ky) * 42 + (px + kx)],
                                 W[W3_OFF + (c * 5 + ky) * 5 + kx], a);
                    }
                }
            }
            float y = fmaf(a, W[SC3_OFF], W[SH3_OFF]);
            float s = 1.f / (1.f + expf(-y));
            d = (int)floorf(s * (16.f - 1e-5f));
        }
        dtile[py][px] = d;
    }
    __syncthreads();

    // phase 3: overwrite u with fwl [s][20]
    for (int i = tid; i < 6860; i += 512) u[i] = W[FWT_OFF + i];
    __syncthreads();

    // phase 4: sparse 3d gather, dy split across halves
    int d0 = dtile[ty + 3][tx + 3];
    float a0, a1, a2, a3;
    if (hi == 0) { a0 = fb[0]; a1 = fb[1]; a2 = fb[2]; a3 = fb[3]; }
    else         { a0 = 0.f;   a1 = 0.f;   a2 = 0.f;   a3 = 0.f;   }
    int dy_lo = hi ? 4 : 0;
    int dy_hi = hi ? 7 : 4;

#pragma unroll 1
    for (int dy = dy_lo; dy < dy_hi; ++dy) {
#pragma unroll
        for (int dx = 0; dx < 7; ++dx) {
            int dd = dtile[ty + dy][tx + dx];
            int dz = dd - d0 + 3;
            if ((unsigned)dz < 7u) {
                int s = (dz * 7 + dy) * 7 + dx;
                const float* fs = u + s * 20;   // k = o*4 + c
                float4 w0 = *(const float4*)(fs);
                float4 w1 = *(const float4*)(fs + 4);
                float4 w2 = *(const float4*)(fs + 8);
                float4 w3 = *(const float4*)(fs + 12);
                float l0 = ltile[0][ty + dy][tx + dx];
                float l1 = ltile[1][ty + dy][tx + dx];
                float l2 = ltile[2][ty + dy][tx + dx];
                a0 += l0 * w0.x + l1 * w0.y + l2 * w0.z + w0.w;
                a1 += l0 * w1.x + l1 * w1.y + l2 * w1.z + w1.w;
                a2 += l0 * w2.x + l1 * w2.y + l2 * w2.z + w2.w;
                a3 += l0 * w3.x + l1 * w3.y + l2 * w3.z + w3.w;
            }
        }
    }

    if (hi == 1)
        *(float4*)&red[pslot * 4] = make_float4(a0, a1, a2, a3);
    __syncthreads();
    if (hi == 0) {
        float4 t = *(const float4*)&red[pslot * 4];
        a0 += t.x; a1 += t.y; a2 += t.z; a3 += t.w;
        int gy = by * 8 + ty, gx = bx * 32 + tx;
        int pix = gy * HW + gx;
        out[0 * PLANE + pix] = a0 / a3 * albedo[0 * PLANE + pix];
        out[1 * PLANE + pix] = a1 / a3 * albedo[1 * PLANE + pix];
        out[2 * PLANE + pix] = a2 / a3 * albedo[2 * PLANE + pix];
    }
}

extern "C" void kernel_launch(void* const* d_in, const int* in_sizes, int n_in,
                              void* d_out, int out_size, void* d_ws, size_t ws_size,
                              hipStream_t stream) {
    const float* light     = (const float*)d_in[0];
    const float* albedo    = (const float*)d_in[1];
    const float* normals   = (const float*)d_in[2];
    const float* c1_w = (const float*)d_in[4];
    const float* c1_b = (const float*)d_in[5];
    const float* bn1_g = (const float*)d_in[6];
    const float* bn1_b = (const float*)d_in[7];
    const float* bn1_m = (const float*)d_in[8];
    const float* bn1_v = (const float*)d_in[9];
    const float* c2_w = (const float*)d_in[10];
    const float* c2_b = (const float*)d_in[11];
    const float* bn2_g = (const float*)d_in[12];
    const float* bn2_b = (const float*)d_in[13];
    const float* bn2_m = (const float*)d_in[14];
    const float* bn2_v = (const float*)d_in[15];
    const float* c3_w = (const float*)d_in[16];
    const float* c3_b = (const float*)d_in[17];
    const float* bn3_g = (const float*)d_in[18];
    const float* bn3_b = (const float*)d_in[19];
    const float* bn3_m = (const float*)d_in[20];
    const float* bn3_v = (const float*)d_in[21];
    const float* f_w = (const float*)d_in[22];
    const float* f_b = (const float*)d_in[23];

    float* W = (float*)d_ws;
    float* h1 = W + H1_OFF;
    float* h2p = W + H2P_OFF;
    float* h2 = W + H2S_OFF;
    float* out = (float*)d_out;

    hipLaunchKernelGGL(prep_kernel, dim3(16), dim3(256), 0, stream,
                       c1_w, c1_b, bn1_g, bn1_b, bn1_m, bn1_v,
                       c2_w, c2_b, bn2_g, bn2_b, bn2_m, bn2_v,
                       c3_w, c3_b, bn3_g, bn3_b, bn3_m, bn3_v,
                       f_w, W);
    hipLaunchKernelGGL(conv1_kernel, dim3(1152), dim3(256), 0, stream,
                       light, albedo, normals, W, h1);
    hipLaunchKernelGGL(conv2_kernel, dim3(2304), dim3(256), 0, stream,
                       h1, W, h2p);
    hipLaunchKernelGGL(combine_kernel, dim3(1152), dim3(256), 0, stream,
                       h2p, W, h2);
    hipLaunchKernelGGL(final_kernel, dim3(576), dim3(512), 0, stream,
                       light, albedo, h2, W, f_b, out);
}